// Round 1
// baseline (691.363 us; speedup 1.0000x reference)
//
#include <hip/hip_runtime.h>

// ALSH conv setup: hash kernels, vote via 1-channel conv, histogram, argmax,
// gather active kernel set.
//
// Constants from the reference:
#define O_CH   256      // out_channels
#define C_CH   64       // in_channels
#define FLATK  576      // C*K*K
#define M_TERMS 9
#define AL     585      // D*K*K = (C + 1)*9
#define TSZ    8192     // table size
#define RADIUS 4.0f
#define NB     16
#define HH     256
#define WW     256

// workspace layout (ints):
//   [0, 256)            k_idx   : bucket of each kernel
//   [256, 256+8192)     hist    : vote histogram
//   [8448]              best    : argmax bucket
//   [8449, 8449+512)    rows    : active kernel ids (-1 = empty slot)
#define WS_KIDX 0
#define WS_HIST 256
#define WS_BEST (256 + TSZ)
#define WS_ROWS (256 + TSZ + 1)

// ---------------- K1: hash kernels + zero histogram ----------------
__global__ void k_init(const float* __restrict__ kernels,
                       const float* __restrict__ a,
                       const float* __restrict__ b,
                       int* __restrict__ ws) {
    if (blockIdx.x == 0) {
        int o = threadIdx.x;
        if (o < O_CH) {
            const float* w = kernels + o * FLATK;
            float dot = 0.f, n2 = 0.f;
            for (int j = 0; j < FLATK; ++j) {
                float x = w[j];
                dot += x * a[j];
                n2  += x * x;
            }
            float p = n2;
            for (int i = 0; i < M_TERMS; ++i) { dot += p * a[FLATK + i]; p *= n2; }
            float hk = floorf((dot + b[0]) / RADIUS);
            int id = (int)fabsf(fmodf(hk, (float)TSZ));
            ws[WS_KIDX + o] = id;
        }
    } else {
        int t = (blockIdx.x - 1) * blockDim.x + threadIdx.x;
        if (t < TSZ) ws[WS_HIST + t] = 0;
    }
}

// ---------------- K2: vote conv + LDS histogram ----------------
#define TX 32
#define TY 8
__global__ __launch_bounds__(256) void k_vote(const float* __restrict__ input,
                                              const float* __restrict__ a,
                                              const float* __restrict__ b,
                                              int* __restrict__ ws) {
    __shared__ int   hist_s[TSZ];          // 32 KB
    __shared__ float a_s[AL];              // 2.3 KB
    __shared__ float tile[TY + 2][TX + 2]; // 1.4 KB
    const int tid = threadIdx.x;

    for (int i = tid; i < TSZ; i += 256) hist_s[i] = 0;
    for (int i = tid; i < AL; i += 256) a_s[i] = a[i];
    __syncthreads();

    const float bv = b[0];
    const int px = tid & 31;       // 0..31
    const int py = tid >> 5;       // 0..7
    const int tilesX = WW / TX;            // 8
    const int tilesY = HH / TY;            // 32
    const int tilesPerImg = tilesX * tilesY; // 256
    const int totalTiles = NB * tilesPerImg; // 4096
    int* hist_g = ws + WS_HIST;

    for (int t = blockIdx.x; t < totalTiles; t += gridDim.x) {
        int n  = t / tilesPerImg;
        int rt = t - n * tilesPerImg;
        int ty = rt / tilesX;
        int tx = rt - ty * tilesX;
        int y0 = ty * TY, x0 = tx * TX;

        float acc = 0.f;
        for (int c = 0; c < C_CH; ++c) {
            __syncthreads();   // protect previous iteration's tile reads
            const float* src = input + ((size_t)(n * C_CH + c)) * (HH * WW);
            for (int i = tid; i < (TY + 2) * (TX + 2); i += 256) {
                int ly = i / (TX + 2);
                int lx = i - ly * (TX + 2);
                int gy = y0 + ly - 1, gx = x0 + lx - 1;
                float v = 0.f;
                if (gy >= 0 && gy < HH && gx >= 0 && gx < WW)
                    v = src[gy * WW + gx];
                tile[ly][lx] = v;
            }
            __syncthreads();
            const float* ac = a_s + c * 9;
            #pragma unroll
            for (int ky = 0; ky < 3; ++ky)
                #pragma unroll
                for (int kx = 0; kx < 3; ++kx)
                    acc += tile[py + ky][px + kx] * ac[ky * 3 + kx];
        }

        // constant Q-channel: value 0.5 inside the image, zero-padded outside
        {
            const float* ac = a_s + FLATK;
            float cs = 0.f;
            int gy = y0 + py, gx = x0 + px;
            #pragma unroll
            for (int ky = 0; ky < 3; ++ky) {
                int yy = gy + ky - 1;
                if (yy < 0 || yy >= HH) continue;
                #pragma unroll
                for (int kx = 0; kx < 3; ++kx) {
                    int xx = gx + kx - 1;
                    if (xx < 0 || xx >= WW) continue;
                    cs += ac[ky * 3 + kx];
                }
            }
            acc += 0.5f * cs;
        }

        float v = floorf((acc + bv) / RADIUS);
        int vi = (int)fabsf(fmodf(v, (float)TSZ));
        atomicAdd(&hist_s[vi], 1);
    }

    __syncthreads();
    for (int i = tid; i < TSZ; i += 256) {
        int v = hist_s[i];
        if (v) atomicAdd(&hist_g[i], v);
    }
}

// ---------------- K3: argmax + count output + active row list ----------------
__global__ void k_finalize(int* __restrict__ ws, float* __restrict__ out) {
    __shared__ int sv[256], si[256];
    const int tid = threadIdx.x;
    const int* hist = ws + WS_HIST;

    int best = -1, bidx = 0;
    for (int t = tid; t < TSZ; t += 256) {
        int v = hist[t];
        if (v > best) { best = v; bidx = t; }  // strict > keeps first occurrence
    }
    sv[tid] = best; si[tid] = bidx;
    __syncthreads();
    for (int s = 128; s > 0; s >>= 1) {
        if (tid < s) {
            if (sv[tid + s] > sv[tid] ||
                (sv[tid + s] == sv[tid] && si[tid + s] < si[tid])) {
                sv[tid] = sv[tid + s]; si[tid] = si[tid + s];
            }
        }
        __syncthreads();
    }
    const int bestIdx = si[0];

    // count (float) + index
    float* count_out = out + 512 * FLATK;
    for (int t = tid; t < TSZ; t += 256) count_out[t] = (float)hist[t];

    if (tid == 0) {
        out[512 * FLATK + TSZ] = (float)bestIdx;
        ws[WS_BEST] = bestIdx;
        int* rows = ws + WS_ROWS;
        int cnt = 0;
        const int* k_idx = ws + WS_KIDX;
        // insertion order is ascending kernel id -> already sorted
        for (int o = 0; o < O_CH; ++o)
            if (k_idx[o] == bestIdx) rows[cnt++] = o;
        for (int s = cnt; s < 2 * O_CH; ++s) rows[s] = -1;
    }
}

// ---------------- K4: gather active kernels ----------------
__global__ void k_gather(const float* __restrict__ kernels,
                         const int* __restrict__ ws,
                         float* __restrict__ out) {
    int gid = blockIdx.x * blockDim.x + threadIdx.x;
    if (gid >= 2 * O_CH * FLATK) return;
    int s = gid / FLATK;
    int j = gid - s * FLATK;
    int r = ws[WS_ROWS + s];
    out[gid] = (r >= 0) ? kernels[r * FLATK + j] : 0.0f;
}

extern "C" void kernel_launch(void* const* d_in, const int* in_sizes, int n_in,
                              void* d_out, int out_size, void* d_ws, size_t ws_size,
                              hipStream_t stream) {
    const float* input   = (const float*)d_in[0];
    const float* kernels = (const float*)d_in[1];
    const float* a       = (const float*)d_in[2];
    const float* b       = (const float*)d_in[3];
    float* out = (float*)d_out;
    int*   ws  = (int*)d_ws;

    k_init<<<1 + TSZ / 256, 256, 0, stream>>>(kernels, a, b, ws);
    k_vote<<<1024, 256, 0, stream>>>(input, a, b, ws);
    k_finalize<<<1, 256, 0, stream>>>(ws, out);
    k_gather<<<(2 * O_CH * FLATK + 255) / 256, 256, 0, stream>>>(kernels, ws, out);
}

// Round 2
// 408.517 us; speedup vs baseline: 1.6924x; 1.6924x over previous
//
#include <hip/hip_runtime.h>

// ALSH conv setup: hash kernels, vote via 1-channel conv, histogram, argmax,
// gather active kernel set.
#define O_CH   256      // out_channels
#define C_CH   64       // in_channels
#define FLATK  576      // C*K*K
#define M_TERMS 9
#define AL     585      // D*K*K = (C + 1)*9
#define TSZ    8192     // table size
#define RADIUS 4.0f
#define NB     16
#define HH     256
#define WW     256

// workspace layout (ints):
//   [0, 256)            k_idx : bucket of each kernel
//   [256, 256+8192)     hist  : vote histogram
//   [8448]              best  : argmax bucket
//   [8449, 8449+512)    rows  : active kernel ids (-1 = empty slot)
#define WS_KIDX 0
#define WS_HIST 256
#define WS_BEST (256 + TSZ)
#define WS_ROWS (256 + TSZ + 1)

// ---------------- K1: hash kernels (1 wave per kernel) + zero histogram ----
__global__ __launch_bounds__(256) void k_init(const float* __restrict__ kernels,
                                              const float* __restrict__ a,
                                              const float* __restrict__ b,
                                              int* __restrict__ ws) {
    if (blockIdx.x < 64) {
        const int wv = threadIdx.x >> 6, lane = threadIdx.x & 63;
        const int o = blockIdx.x * 4 + wv;
        const float* wp = kernels + o * FLATK;
        float dot = 0.f, n2 = 0.f;
        #pragma unroll
        for (int j0 = 0; j0 < FLATK; j0 += 64) {   // 576/64 = 9 coalesced rounds
            float x = wp[j0 + lane];
            dot += x * a[j0 + lane];
            n2  += x * x;
        }
        #pragma unroll
        for (int off = 32; off > 0; off >>= 1) {
            dot += __shfl_xor(dot, off);
            n2  += __shfl_xor(n2, off);
        }
        if (lane == 0) {
            float p = n2, d = dot;
            for (int i = 0; i < M_TERMS; ++i) { d += p * a[FLATK + i]; p *= n2; }
            float hk = floorf((d + b[0]) / RADIUS);
            ws[WS_KIDX + o] = (int)fabsf(fmodf(hk, (float)TSZ));
        }
    } else {
        int t = (blockIdx.x - 64) * 256 + threadIdx.x;
        ws[WS_HIST + t] = 0;
    }
}

// ---------------- K2: vote conv, register-tiled, barrier-free main loop ----
// Block: 256 threads -> tile 256 wide x 8 tall. Thread: 4 px wide x 2 rows.
#define TILE_H 8
__global__ __launch_bounds__(256) void k_vote(const float* __restrict__ input,
                                              const float* __restrict__ a,
                                              const float* __restrict__ b,
                                              int* __restrict__ ws) {
    __shared__ int   hist_s[TSZ];   // 32 KB
    __shared__ float a_s[AL];
    const int tid = threadIdx.x;

    for (int i = tid; i < TSZ; i += 256) hist_s[i] = 0;
    for (int i = tid; i < AL; i += 256) a_s[i] = a[i];
    __syncthreads();

    const float bv = b[0];
    const int by = blockIdx.x & 31;        // 32 row-tiles per image
    const int n  = blockIdx.x >> 5;        // 16 images
    const int y0 = by * TILE_H;
    const int xg = tid & 63;               // 64 x-groups
    const int yg = tid >> 6;               // 4 y-groups
    const int x4 = xg * 4;                 // columns x4..x4+3
    const int ybase = y0 + yg * 2;         // rows ybase, ybase+1

    float acc[2][4] = {{0.f,0.f,0.f,0.f},{0.f,0.f,0.f,0.f}};
    const float* imgbase = input + (size_t)n * C_CH * HH * WW;

    #pragma unroll 2
    for (int c = 0; c < C_CH; ++c) {
        const float* src = imgbase + (size_t)c * (HH * WW);
        float w[4][6];
        #pragma unroll
        for (int r = 0; r < 4; ++r) {      // input rows ybase-1 .. ybase+2
            int gy = ybase - 1 + r;
            if (gy >= 0 && gy < HH) {      // wave-uniform branch
                const float* rp = src + gy * WW + x4;
                float4 v = *(const float4*)rp;
                w[r][1] = v.x; w[r][2] = v.y; w[r][3] = v.z; w[r][4] = v.w;
                w[r][0] = (x4 > 0)       ? rp[-1] : 0.f;
                w[r][5] = (x4 + 4 < WW)  ? rp[4]  : 0.f;
            } else {
                #pragma unroll
                for (int q = 0; q < 6; ++q) w[r][q] = 0.f;
            }
        }
        const float* ac = a_s + c * 9;
        #pragma unroll
        for (int rr = 0; rr < 2; ++rr)
            #pragma unroll
            for (int ky = 0; ky < 3; ++ky)
                #pragma unroll
                for (int p = 0; p < 4; ++p)
                    #pragma unroll
                    for (int kx = 0; kx < 3; ++kx)
                        acc[rr][p] += w[rr + ky][p + kx] * ac[ky * 3 + kx];
    }

    // constant Q-channel (0.5 inside image, zero-padded) + vote
    #pragma unroll
    for (int rr = 0; rr < 2; ++rr) {
        int gy = ybase + rr;
        #pragma unroll
        for (int p = 0; p < 4; ++p) {
            int gx = x4 + p;
            float cs = 0.f;
            #pragma unroll
            for (int ky = 0; ky < 3; ++ky) {
                int yy = gy + ky - 1;
                if (yy < 0 || yy >= HH) continue;
                #pragma unroll
                for (int kx = 0; kx < 3; ++kx) {
                    int xx = gx + kx - 1;
                    if (xx < 0 || xx >= WW) continue;
                    cs += a_s[FLATK + ky * 3 + kx];
                }
            }
            float t = acc[rr][p] + 0.5f * cs;
            float v = floorf((t + bv) / RADIUS);
            int vi = (int)fabsf(fmodf(v, (float)TSZ));
            atomicAdd(&hist_s[vi], 1);
        }
    }

    __syncthreads();
    int* hist_g = ws + WS_HIST;
    for (int i = tid; i < TSZ; i += 256) {
        int v = hist_s[i];
        if (v) atomicAdd(&hist_g[i], v);
    }
}

// ---------------- K3: argmax + count output + active row list (parallel) ---
__global__ __launch_bounds__(256) void k_finalize(int* __restrict__ ws,
                                                  float* __restrict__ out) {
    __shared__ int sv[256], si[256];
    __shared__ int wsum[4];
    const int tid = threadIdx.x;
    const int* hist = ws + WS_HIST;

    int best = -1, bidx = 0;
    for (int t = tid; t < TSZ; t += 256) {
        int v = hist[t];
        if (v > best) { best = v; bidx = t; }  // strict > keeps first occurrence
    }
    sv[tid] = best; si[tid] = bidx;
    __syncthreads();
    for (int s = 128; s > 0; s >>= 1) {
        if (tid < s) {
            if (sv[tid + s] > sv[tid] ||
                (sv[tid + s] == sv[tid] && si[tid + s] < si[tid])) {
                sv[tid] = sv[tid + s]; si[tid] = si[tid + s];
            }
        }
        __syncthreads();
    }
    const int bestIdx = si[0];

    // count (float) + index, coalesced
    float* count_out = out + 512 * FLATK;
    for (int t = tid; t < TSZ; t += 256) count_out[t] = (float)hist[t];
    if (tid == 0) {
        out[512 * FLATK + TSZ] = (float)bestIdx;
        ws[WS_BEST] = bestIdx;
    }

    // active rows via ballot prefix-scan (insertion order = ascending id)
    int* rows = ws + WS_ROWS;
    for (int i = tid; i < 2 * O_CH; i += 256) rows[i] = -1;
    const int o = tid;
    const int match = (ws[WS_KIDX + o] == bestIdx) ? 1 : 0;
    unsigned long long m = __ballot(match);
    const int lane = tid & 63, wv = tid >> 6;
    if (lane == 0) wsum[wv] = __popcll(m);
    __syncthreads();   // also orders the -1 fill before the scatter
    int prefix = 0;
    for (int i = 0; i < wv; ++i) prefix += wsum[i];
    int before = __popcll(m & ((1ull << lane) - 1ull));
    if (match) rows[prefix + before] = o;
}

// ---------------- K4: gather active kernels ----------------
__global__ void k_gather(const float* __restrict__ kernels,
                         const int* __restrict__ ws,
                         float* __restrict__ out) {
    int gid = blockIdx.x * blockDim.x + threadIdx.x;
    if (gid >= 2 * O_CH * FLATK) return;
    int s = gid / FLATK;
    int j = gid - s * FLATK;
    int r = ws[WS_ROWS + s];
    out[gid] = (r >= 0) ? kernels[r * FLATK + j] : 0.0f;
}

extern "C" void kernel_launch(void* const* d_in, const int* in_sizes, int n_in,
                              void* d_out, int out_size, void* d_ws, size_t ws_size,
                              hipStream_t stream) {
    const float* input   = (const float*)d_in[0];
    const float* kernels = (const float*)d_in[1];
    const float* a       = (const float*)d_in[2];
    const float* b       = (const float*)d_in[3];
    float* out = (float*)d_out;
    int*   ws  = (int*)d_ws;

    k_init<<<96, 256, 0, stream>>>(kernels, a, b, ws);
    k_vote<<<NB * (HH / TILE_H), 256, 0, stream>>>(input, a, b, ws);
    k_finalize<<<1, 256, 0, stream>>>(ws, out);
    k_gather<<<(2 * O_CH * FLATK + 255) / 256, 256, 0, stream>>>(kernels, ws, out);
}